// Round 6
// baseline (1277.809 us; speedup 1.0000x reference)
//
#include <hip/hip_runtime.h>
#include <math.h>

// Problem constants (match reference)
#define CUTOFF_F 10.0f
#define PI_OVER_CUTOFF 0.31415926535897931f  // pi/10

// ===========================================================================
// Pass 1: direct fp32 atomic aggregation. One thread per edge; kept edges
// fire 16 no-return unsafeAtomicAdd (native global_atomic_add_f32) into the
// node's single 64B aggr line. ~13 hits per address (low contention, the
// regime R0/R1 proved cheap). No payload, no bucket, no tickets.
// ===========================================================================
__global__ __launch_bounds__(256) void edge_atomic(
    const float* __restrict__ gds,
    const int* __restrict__ eidx,
    const float* __restrict__ edge_sca,
    const float* __restrict__ edge_vec,
    float* __restrict__ aggr,    // [N*16] zeroed
    int E)
{
    int e = blockIdx.x * 256 + threadIdx.x;
    if (e >= E) return;

    float d = gds[e];
    if (d < 0.0f || d > CUTOFF_F) return;   // coeff==0 -> drop (~17%)

    float c = 0.5f * (__cosf(d * PI_OVER_CUTOFF) + 1.0f);
    int src = eidx[e];
    const float* es = edge_sca + (size_t)e * 6;
    const float* ev = edge_vec + (size_t)e * 9;
    float* base = aggr + (size_t)src * 16;

    // 16 independent fire-and-forget atomics, all within one 64B line
    unsafeAtomicAdd(base + 0,  c * es[0]);
    unsafeAtomicAdd(base + 1,  c * es[1]);
    unsafeAtomicAdd(base + 2,  c * es[2]);
    unsafeAtomicAdd(base + 3,  c * es[3]);
    unsafeAtomicAdd(base + 4,  c * es[4]);
    unsafeAtomicAdd(base + 5,  c * es[5]);
    unsafeAtomicAdd(base + 6,  c);
    unsafeAtomicAdd(base + 7,  c * ev[0]);
    unsafeAtomicAdd(base + 8,  c * ev[1]);
    unsafeAtomicAdd(base + 9,  c * ev[2]);
    unsafeAtomicAdd(base + 10, c * ev[3]);
    unsafeAtomicAdd(base + 11, c * ev[4]);
    unsafeAtomicAdd(base + 12, c * ev[5]);
    unsafeAtomicAdd(base + 13, c * ev[6]);
    unsafeAtomicAdd(base + 14, c * ev[7]);
    unsafeAtomicAdd(base + 15, c * ev[8]);
}

// ===========================================================================
// Pass 2: node pipeline (verified structure). 16 lanes per node, 16 nodes
// per 256-block; reads aggr directly (coalesced 64B per node).
// ===========================================================================
__global__ __launch_bounds__(256) void node_lite(
    const float* __restrict__ node_sca,
    const float* __restrict__ node_vec,
    const float* __restrict__ aggr,
    const float* __restrict__ W_nss, const float* __restrict__ b_nss,
    const float* __restrict__ W_ess, const float* __restrict__ b_ess,
    const float* __restrict__ W_nsv, const float* __restrict__ b_nsv,
    const float* __restrict__ W_esv, const float* __restrict__ b_esv,
    const float* __restrict__ W_nvv, const float* __restrict__ W_evv,
    const float* __restrict__ W_lv,  const float* __restrict__ W_lv2,
    const float* __restrict__ W_ls,
    const float* __restrict__ W_gate, const float* __restrict__ b_gate,
    const float* __restrict__ W_dir,
    float* __restrict__ out,
    int N)
{
    // ---- weights in LDS ----
    __shared__ float sW_nss[64],  sb_nss[16];
    __shared__ float sW_ess[96],  sb_ess[16];
    __shared__ float sW_nsv[64],  sb_nsv[16];
    __shared__ float sW_esv[96],  sb_esv[16];
    __shared__ float sW_nvv[48],  sW_evv[48];
    __shared__ float sW_lv[256],  sW_lv2[256];
    __shared__ float sW_ls[512];
    __shared__ float sW_gate[256], sb_gate[16];
    __shared__ float sW_dir[256];

    // ---- per-node scratch (odd node-strides -> no bank conflicts) ----
    __shared__ float s_in  [16 * 33];
    __shared__ float s_avec[16 * 49];
    __shared__ float s_cat [16 * 33];
    __shared__ float s_vint[16 * 49];
    __shared__ float s_osca[16 * 17];
    __shared__ float s_ovec[16 * 49];

    const int t = threadIdx.x;
    {
        for (int i = t; i < 64;  i += 256) { sW_nss[i] = W_nss[i]; sW_nsv[i] = W_nsv[i]; }
        for (int i = t; i < 96;  i += 256) { sW_ess[i] = W_ess[i]; sW_esv[i] = W_esv[i]; }
        for (int i = t; i < 48;  i += 256) { sW_nvv[i] = W_nvv[i]; sW_evv[i] = W_evv[i]; }
        for (int i = t; i < 256; i += 256) {
            sW_lv[i]   = W_lv[i];
            sW_lv2[i]  = W_lv2[i];
            sW_gate[i] = W_gate[i];
            sW_dir[i]  = W_dir[i];
        }
        for (int i = t; i < 512; i += 256) sW_ls[i] = W_ls[i];
        if (t < 16) {
            sb_nss[t]  = b_nss[t];
            sb_ess[t]  = b_ess[t];
            sb_nsv[t]  = b_nsv[t];
            sb_esv[t]  = b_esv[t];
            sb_gate[t] = b_gate[t];
        }
    }

    const int slot = t >> 4;
    const int o    = t & 15;
    const int n    = blockIdx.x * 16 + slot;
    const bool valid = (n < N);

    if (valid) {
        if (o < 4) s_in[slot * 33 + o]     = node_sca[(size_t)n * 4 + o];
        if (o < 9) s_in[slot * 33 + 4 + o] = node_vec[(size_t)n * 9 + o];
        s_in[slot * 33 + 13 + o] = aggr[(size_t)n * 16 + o];
    }
    __syncthreads();

    const float* in = s_in + slot * 33;

    float nss = sb_nss[o], nsv = sb_nsv[o];
#pragma unroll
    for (int c = 0; c < 4; ++c) {
        float x = in[c];
        nss += x * sW_nss[c * 16 + o];
        nsv += x * sW_nsv[c * 16 + o];
    }
    float nvv0 = 0.f, nvv1 = 0.f, nvv2 = 0.f;
#pragma unroll
    for (int c = 0; c < 3; ++c) {
        float w = sW_nvv[c * 16 + o];
        nvv0 += in[4 + c * 3 + 0] * w;
        nvv1 += in[4 + c * 3 + 1] * w;
        nvv2 += in[4 + c * 3 + 2] * w;
    }
    float cc = in[19];
    float es = cc * sb_ess[o], ev = cc * sb_esv[o];
#pragma unroll
    for (int c = 0; c < 6; ++c) {
        float a = in[13 + c];
        es += a * sW_ess[c * 16 + o];
        ev += a * sW_esv[c * 16 + o];
    }
    float EV0 = 0.f, EV1 = 0.f, EV2 = 0.f;
#pragma unroll
    for (int c = 0; c < 3; ++c) {
        float w = sW_evv[c * 16 + o];
        EV0 += in[20 + c * 3 + 0] * w;
        EV1 += in[20 + c * 3 + 1] * w;
        EV2 += in[20 + c * 3 + 2] * w;
    }

    float asca = nss * es;
    float av0 = nvv0 * ev + nsv * EV0;
    float av1 = nvv1 * ev + nsv * EV1;
    float av2 = nvv2 * ev + nsv * EV2;
    s_avec[slot * 49 + o * 3 + 0] = av0;
    s_avec[slot * 49 + o * 3 + 1] = av1;
    s_avec[slot * 49 + o * 3 + 2] = av2;
    s_cat[slot * 33 + 16 + o] = asca;
    __syncthreads();

    float vi0 = 0.f, vi1 = 0.f, vi2 = 0.f;
#pragma unroll
    for (int c = 0; c < 16; ++c) {
        float w = sW_lv[c * 16 + o];
        const float* a = &s_avec[slot * 49 + c * 3];
        vi0 += a[0] * w; vi1 += a[1] * w; vi2 += a[2] * w;
    }
    float vnorm = sqrtf(vi0 * vi0 + vi1 * vi1 + vi2 * vi2);
    s_vint[slot * 49 + o * 3 + 0] = vi0;
    s_vint[slot * 49 + o * 3 + 1] = vi1;
    s_vint[slot * 49 + o * 3 + 2] = vi2;
    s_cat[slot * 33 + o] = vnorm;
    __syncthreads();

    float osca = 0.f;
#pragma unroll
    for (int c = 0; c < 32; ++c)
        osca += s_cat[slot * 33 + c] * sW_ls[c * 16 + o];
    float ov0 = 0.f, ov1 = 0.f, ov2 = 0.f;
#pragma unroll
    for (int c = 0; c < 16; ++c) {
        float w = sW_lv2[c * 16 + o];
        const float* a = &s_vint[slot * 49 + c * 3];
        ov0 += a[0] * w; ov1 += a[1] * w; ov2 += a[2] * w;
    }
    s_osca[slot * 17 + o] = osca;
    __syncthreads();

    float g = sb_gate[o];
#pragma unroll
    for (int c = 0; c < 16; ++c)
        g += s_osca[slot * 17 + c] * sW_gate[c * 16 + o];
    g = 1.0f / (1.0f + __expf(-g));
    ov0 *= g; ov1 *= g; ov2 *= g;
    s_ovec[slot * 49 + o * 3 + 0] = ov0;
    s_ovec[slot * 49 + o * 3 + 1] = ov1;
    s_ovec[slot * 49 + o * 3 + 2] = ov2;
    __syncthreads();

    float dv0 = 0.f, dv1 = 0.f, dv2 = 0.f;
#pragma unroll
    for (int c = 0; c < 16; ++c) {
        float w = sW_dir[c * 16 + o];
        const float* a = &s_ovec[slot * 49 + c * 3];
        dv0 += a[0] * w; dv1 += a[1] * w; dv2 += a[2] * w;
    }
    float dot = ov0 * dv0 + ov1 * dv1 + ov2 * dv2;
    if (dot < 0.0f) {
        float dn = dv0 * dv0 + dv1 * dv1 + dv2 * dv2;
        float f = 0.8f * dot / (dn + 1e-6f);
        ov0 -= f * dv0; ov1 -= f * dv1; ov2 -= f * dv2;
    }

    if (valid) {
        float so = (osca >= 0.0f) ? osca : 0.01f * osca;
        out[(size_t)n * 16 + o] = so;
        size_t vb = (size_t)N * 16 + (size_t)n * 48 + (size_t)o * 3;
        out[vb + 0] = ov0;
        out[vb + 1] = ov1;
        out[vb + 2] = ov2;
    }
}

extern "C" void kernel_launch(void* const* d_in, const int* in_sizes, int n_in,
                              void* d_out, int out_size, void* d_ws, size_t ws_size,
                              hipStream_t stream)
{
    const float* node_sca = (const float*)d_in[0];
    const float* node_vec = (const float*)d_in[1];
    const float* edge_sca = (const float*)d_in[2];
    const float* edge_vec = (const float*)d_in[3];
    const float* gds      = (const float*)d_in[4];
    const int*   eidx     = (const int*)d_in[5];

    const int N = in_sizes[0] / 4;   // node_sca is [N,4]
    const int E = in_sizes[4];       // gds_dist is [E]

    float* aggr = (float*)d_ws;      // [N*16] fp32

    hipMemsetAsync(aggr, 0, (size_t)N * 64, stream);
    edge_atomic<<<(E + 255) / 256, 256, 0, stream>>>(
        gds, eidx, edge_sca, edge_vec, aggr, E);
    node_lite<<<(N + 15) / 16, 256, 0, stream>>>(
        node_sca, node_vec, aggr,
        (const float*)d_in[6],  (const float*)d_in[7],
        (const float*)d_in[8],  (const float*)d_in[9],
        (const float*)d_in[10], (const float*)d_in[11],
        (const float*)d_in[12], (const float*)d_in[13],
        (const float*)d_in[14], (const float*)d_in[15],
        (const float*)d_in[16], (const float*)d_in[17],
        (const float*)d_in[18],
        (const float*)d_in[19], (const float*)d_in[20],
        (const float*)d_in[21],
        (float*)d_out, N);
}

// Round 7
// 289.124 us; speedup vs baseline: 4.4196x; 4.4196x over previous
//
#include <hip/hip_runtime.h>
#include <hip/hip_fp16.h>
#include <math.h>

// Problem constants (match reference)
#define CUTOFF_F 10.0f
#define PI_OVER_CUTOFF 0.31415926535897931f  // pi/10
#define KCAP 32   // fp16 payload slots per node (32B each)

// ===========================================================================
// Pass 1 (R0 structure + cutoff drop): one thread per edge. Kept edges take a
// per-node ticket (low contention, ~13 hits/addr — proven cheap in R0/R1) and
// write one 32B packed-fp16 record at [src][slot]. Entries with coeff==0
// (~17%) are dropped BEFORE the ticket: write drain 102 -> ~85 MB and
// phase-2 cnt shrinks 16 -> 13.3. Overflow (slot>=KCAP, ~+5sigma) -> fp32
// atomics into aggr (rare; correctness only).
// ===========================================================================
__global__ __launch_bounds__(256) void bucket_scatter(
    const float* __restrict__ gds,
    const int* __restrict__ eidx,
    const float* __restrict__ edge_sca,
    const float* __restrict__ edge_vec,
    int* __restrict__ count,      // [N] zeroed
    __half* __restrict__ bucket,  // [N*KCAP*16] halfs
    float* __restrict__ aggr,     // [N*16] zeroed overflow accumulator
    int E)
{
    int e = blockIdx.x * 256 + threadIdx.x;
    if (e >= E) return;

    float d = gds[e];
    if (d < 0.0f || d > CUTOFF_F) return;   // coeff==0 -> contributes nothing

    float c = 0.5f * (__cosf(d * PI_OVER_CUTOFF) + 1.0f);
    int src = eidx[e];
    const float* es = edge_sca + (size_t)e * 6;
    const float* ev = edge_vec + (size_t)e * 9;

    float f[16];
#pragma unroll
    for (int i = 0; i < 6; ++i) f[i] = c * es[i];
    f[6] = c;
#pragma unroll
    for (int i = 0; i < 9; ++i) f[7 + i] = c * ev[i];

    int slot = atomicAdd(&count[src], 1);
    if (slot < KCAP) {
        union { __half h[16]; uint4 u[2]; } pk;
#pragma unroll
        for (int i = 0; i < 16; ++i) pk.h[i] = __float2half(f[i]);
        uint4* pb = (uint4*)(bucket + ((size_t)src * KCAP + slot) * 16);
        pb[0] = pk.u[0];
        pb[1] = pk.u[1];
    } else {
        float* base = aggr + (size_t)src * 16;
#pragma unroll
        for (int i = 0; i < 16; ++i) atomicAdd(base + i, f[i]);
    }
}

// ===========================================================================
// Fallback: pure fp32 atomic aggregation (tiny workspace; ~never taken)
// ===========================================================================
__global__ __launch_bounds__(256) void edge_aggregate(
    const float* __restrict__ edge_sca, const float* __restrict__ edge_vec,
    const float* __restrict__ gds, const int* __restrict__ eidx,
    float* __restrict__ aggr, int E)
{
    int e = blockIdx.x * blockDim.x + threadIdx.x;
    if (e >= E) return;
    int src = eidx[e];
    float d = gds[e];
    float coeff = 0.0f;
    if (d >= 0.0f && d <= CUTOFF_F)
        coeff = 0.5f * (__cosf(d * PI_OVER_CUTOFF) + 1.0f);
    float* base = aggr + (size_t)src * 16;
    const float* es = edge_sca + (size_t)e * 6;
    const float* ev = edge_vec + (size_t)e * 9;
#pragma unroll
    for (int c = 0; c < 6; ++c) atomicAdd(base + c, coeff * es[c]);
    atomicAdd(base + 6, coeff);
#pragma unroll
    for (int k = 0; k < 9; ++k) atomicAdd(base + 7 + k, coeff * ev[k]);
}

// ===========================================================================
// Pass 2: fused node kernel. mode 1: block-cooperative payload reduction —
// the block's 16 nodes own one contiguous 16KB payload region; each thread
// issues up to 4 predicated uint4 (16B) loads (fully coalesced, only cnt
// slots actually read), accumulates 8 features in registers, then a 3-step
// shfl_xor butterfly (lanes 2/4/8) reduces the 8 slot-subgroups.
// Thread t: node = t>>4, o = t&15, h = o&1 (feature half), sg = o>>1 (slot
// subgroup). uint4 #(o + 16k) of the node = slot (sg+8k), features 8h..8h+7.
// mode 0: read aggr directly (fallback).
// ===========================================================================
__global__ __launch_bounds__(256) void node_fused(
    const float* __restrict__ node_sca,
    const float* __restrict__ node_vec,
    const int* __restrict__ count,
    const __half* __restrict__ payload,
    const float* __restrict__ aggr,
    const float* __restrict__ W_nss, const float* __restrict__ b_nss,
    const float* __restrict__ W_ess, const float* __restrict__ b_ess,
    const float* __restrict__ W_nsv, const float* __restrict__ b_nsv,
    const float* __restrict__ W_esv, const float* __restrict__ b_esv,
    const float* __restrict__ W_nvv, const float* __restrict__ W_evv,
    const float* __restrict__ W_lv,  const float* __restrict__ W_lv2,
    const float* __restrict__ W_ls,
    const float* __restrict__ W_gate, const float* __restrict__ b_gate,
    const float* __restrict__ W_dir,
    float* __restrict__ out,
    int N, int mode)
{
    // ---- weights in LDS ----
    __shared__ float sW_nss[64],  sb_nss[16];
    __shared__ float sW_ess[96],  sb_ess[16];
    __shared__ float sW_nsv[64],  sb_nsv[16];
    __shared__ float sW_esv[96],  sb_esv[16];
    __shared__ float sW_nvv[48],  sW_evv[48];
    __shared__ float sW_lv[256],  sW_lv2[256];
    __shared__ float sW_ls[512];
    __shared__ float sW_gate[256], sb_gate[16];
    __shared__ float sW_dir[256];

    // ---- per-node scratch (odd node-strides -> no bank conflicts) ----
    __shared__ float s_in  [16 * 33];
    __shared__ float s_avec[16 * 49];
    __shared__ float s_cat [16 * 33];
    __shared__ float s_vint[16 * 49];
    __shared__ float s_osca[16 * 17];
    __shared__ float s_ovec[16 * 49];

    const int t = threadIdx.x;
    {
        for (int i = t; i < 64;  i += 256) { sW_nss[i] = W_nss[i]; sW_nsv[i] = W_nsv[i]; }
        for (int i = t; i < 96;  i += 256) { sW_ess[i] = W_ess[i]; sW_esv[i] = W_esv[i]; }
        for (int i = t; i < 48;  i += 256) { sW_nvv[i] = W_nvv[i]; sW_evv[i] = W_evv[i]; }
        for (int i = t; i < 256; i += 256) {
            sW_lv[i]   = W_lv[i];
            sW_lv2[i]  = W_lv2[i];
            sW_gate[i] = W_gate[i];
            sW_dir[i]  = W_dir[i];
        }
        for (int i = t; i < 512; i += 256) sW_ls[i] = W_ls[i];
        if (t < 16) {
            sb_nss[t]  = b_nss[t];
            sb_ess[t]  = b_ess[t];
            sb_nsv[t]  = b_nsv[t];
            sb_esv[t]  = b_esv[t];
            sb_gate[t] = b_gate[t];
        }
    }

    const int slot = t >> 4;
    const int o    = t & 15;
    const int n    = blockIdx.x * 16 + slot;
    const bool valid = (n < N);

    if (valid) {
        if (o < 4) s_in[slot * 33 + o]     = node_sca[(size_t)n * 4 + o];
        if (o < 9) s_in[slot * 33 + 4 + o] = node_vec[(size_t)n * 9 + o];
    }

    if (mode == 1) {
        float acc[8] = {0.f, 0.f, 0.f, 0.f, 0.f, 0.f, 0.f, 0.f};
        const int h  = o & 1;
        const int sg = o >> 1;
        if (valid) {
            int cnt = count[n];
            if (cnt > KCAP) cnt = KCAP;
            const uint4* pu = (const uint4*)payload + (size_t)n * (KCAP * 2);
#pragma unroll
            for (int k = 0; k < 4; ++k) {
                int s = sg + 8 * k;
                if (s < cnt) {
                    uint4 v = pu[o + 16 * k];   // coalesced 256B per 16-lane grp
                    const __half2* hp = (const __half2*)&v;
#pragma unroll
                    for (int j = 0; j < 4; ++j) {
                        float2 f2 = __half22float2(hp[j]);
                        acc[2 * j]     += f2.x;
                        acc[2 * j + 1] += f2.y;
                    }
                }
            }
        }
        // butterfly across the 8 slot-subgroups (lane bits 1..3)
#pragma unroll
        for (int m = 2; m <= 8; m <<= 1) {
#pragma unroll
            for (int j = 0; j < 8; ++j)
                acc[j] += __shfl_xor(acc[j], m, 16);
        }
        if (valid && o < 2) {
#pragma unroll
            for (int j = 0; j < 8; ++j)
                s_in[slot * 33 + 13 + 8 * h + j] =
                    acc[j] + aggr[(size_t)n * 16 + 8 * h + j];
        }
    } else {
        if (valid) s_in[slot * 33 + 13 + o] = aggr[(size_t)n * 16 + o];
    }
    __syncthreads();

    const float* in = s_in + slot * 33;

    float nss = sb_nss[o], nsv = sb_nsv[o];
#pragma unroll
    for (int c = 0; c < 4; ++c) {
        float x = in[c];
        nss += x * sW_nss[c * 16 + o];
        nsv += x * sW_nsv[c * 16 + o];
    }
    float nvv0 = 0.f, nvv1 = 0.f, nvv2 = 0.f;
#pragma unroll
    for (int c = 0; c < 3; ++c) {
        float w = sW_nvv[c * 16 + o];
        nvv0 += in[4 + c * 3 + 0] * w;
        nvv1 += in[4 + c * 3 + 1] * w;
        nvv2 += in[4 + c * 3 + 2] * w;
    }
    float cc = in[19];
    float es = cc * sb_ess[o], ev = cc * sb_esv[o];
#pragma unroll
    for (int c = 0; c < 6; ++c) {
        float a = in[13 + c];
        es += a * sW_ess[c * 16 + o];
        ev += a * sW_esv[c * 16 + o];
    }
    float EV0 = 0.f, EV1 = 0.f, EV2 = 0.f;
#pragma unroll
    for (int c = 0; c < 3; ++c) {
        float w = sW_evv[c * 16 + o];
        EV0 += in[20 + c * 3 + 0] * w;
        EV1 += in[20 + c * 3 + 1] * w;
        EV2 += in[20 + c * 3 + 2] * w;
    }

    float asca = nss * es;
    float av0 = nvv0 * ev + nsv * EV0;
    float av1 = nvv1 * ev + nsv * EV1;
    float av2 = nvv2 * ev + nsv * EV2;
    s_avec[slot * 49 + o * 3 + 0] = av0;
    s_avec[slot * 49 + o * 3 + 1] = av1;
    s_avec[slot * 49 + o * 3 + 2] = av2;
    s_cat[slot * 33 + 16 + o] = asca;
    __syncthreads();

    float vi0 = 0.f, vi1 = 0.f, vi2 = 0.f;
#pragma unroll
    for (int c = 0; c < 16; ++c) {
        float w = sW_lv[c * 16 + o];
        const float* a = &s_avec[slot * 49 + c * 3];
        vi0 += a[0] * w; vi1 += a[1] * w; vi2 += a[2] * w;
    }
    float vnorm = sqrtf(vi0 * vi0 + vi1 * vi1 + vi2 * vi2);
    s_vint[slot * 49 + o * 3 + 0] = vi0;
    s_vint[slot * 49 + o * 3 + 1] = vi1;
    s_vint[slot * 49 + o * 3 + 2] = vi2;
    s_cat[slot * 33 + o] = vnorm;
    __syncthreads();

    float osca = 0.f;
#pragma unroll
    for (int c = 0; c < 32; ++c)
        osca += s_cat[slot * 33 + c] * sW_ls[c * 16 + o];
    float ov0 = 0.f, ov1 = 0.f, ov2 = 0.f;
#pragma unroll
    for (int c = 0; c < 16; ++c) {
        float w = sW_lv2[c * 16 + o];
        const float* a = &s_vint[slot * 49 + c * 3];
        ov0 += a[0] * w; ov1 += a[1] * w; ov2 += a[2] * w;
    }
    s_osca[slot * 17 + o] = osca;
    __syncthreads();

    float g = sb_gate[o];
#pragma unroll
    for (int c = 0; c < 16; ++c)
        g += s_osca[slot * 17 + c] * sW_gate[c * 16 + o];
    g = 1.0f / (1.0f + __expf(-g));
    ov0 *= g; ov1 *= g; ov2 *= g;
    s_ovec[slot * 49 + o * 3 + 0] = ov0;
    s_ovec[slot * 49 + o * 3 + 1] = ov1;
    s_ovec[slot * 49 + o * 3 + 2] = ov2;
    __syncthreads();

    float dv0 = 0.f, dv1 = 0.f, dv2 = 0.f;
#pragma unroll
    for (int c = 0; c < 16; ++c) {
        float w = sW_dir[c * 16 + o];
        const float* a = &s_ovec[slot * 49 + c * 3];
        dv0 += a[0] * w; dv1 += a[1] * w; dv2 += a[2] * w;
    }
    float dot = ov0 * dv0 + ov1 * dv1 + ov2 * dv2;
    if (dot < 0.0f) {
        float dn = dv0 * dv0 + dv1 * dv1 + dv2 * dv2;
        float f = 0.8f * dot / (dn + 1e-6f);
        ov0 -= f * dv0; ov1 -= f * dv1; ov2 -= f * dv2;
    }

    if (valid) {
        float so = (osca >= 0.0f) ? osca : 0.01f * osca;
        out[(size_t)n * 16 + o] = so;
        size_t vb = (size_t)N * 16 + (size_t)n * 48 + (size_t)o * 3;
        out[vb + 0] = ov0;
        out[vb + 1] = ov1;
        out[vb + 2] = ov2;
    }
}

extern "C" void kernel_launch(void* const* d_in, const int* in_sizes, int n_in,
                              void* d_out, int out_size, void* d_ws, size_t ws_size,
                              hipStream_t stream)
{
    const float* node_sca = (const float*)d_in[0];
    const float* node_vec = (const float*)d_in[1];
    const float* edge_sca = (const float*)d_in[2];
    const float* edge_vec = (const float*)d_in[3];
    const float* gds      = (const float*)d_in[4];
    const int*   eidx     = (const int*)d_in[5];

    const int N = in_sizes[0] / 4;   // node_sca is [N,4]
    const int E = in_sizes[4];       // gds_dist is [E]

    // ---- layout: [count N ints][aggr N*16 floats][bucket N*KCAP*16 halfs]
    int*    count  = (int*)d_ws;
    float*  aggr   = (float*)(count + N);
    __half* bucket = (__half*)(aggr + (size_t)N * 16);
    size_t  hdr    = (size_t)N * 4 + (size_t)N * 64;
    size_t  need   = hdr + (size_t)N * KCAP * 16 * sizeof(__half);

    if (ws_size >= need) {
        hipMemsetAsync(count, 0, hdr, stream);   // count + aggr adjacent
        bucket_scatter<<<(E + 255) / 256, 256, 0, stream>>>(
            gds, eidx, edge_sca, edge_vec, count, bucket, aggr, E);
        node_fused<<<(N + 15) / 16, 256, 0, stream>>>(
            node_sca, node_vec, count, bucket, aggr,
            (const float*)d_in[6],  (const float*)d_in[7],
            (const float*)d_in[8],  (const float*)d_in[9],
            (const float*)d_in[10], (const float*)d_in[11],
            (const float*)d_in[12], (const float*)d_in[13],
            (const float*)d_in[14], (const float*)d_in[15],
            (const float*)d_in[16], (const float*)d_in[17],
            (const float*)d_in[18],
            (const float*)d_in[19], (const float*)d_in[20],
            (const float*)d_in[21],
            (float*)d_out, N, 1);
        return;
    }

    // ---- fallback: fp32 atomic aggregation, then node pass from aggr ----
    size_t zb = hdr;
    if (zb > ws_size) zb = ws_size;
    hipMemsetAsync(count, 0, zb, stream);
    edge_aggregate<<<(E + 255) / 256, 256, 0, stream>>>(
        edge_sca, edge_vec, gds, eidx, aggr, E);
    node_fused<<<(N + 15) / 16, 256, 0, stream>>>(
        node_sca, node_vec, count, bucket, aggr,
        (const float*)d_in[6],  (const float*)d_in[7],
        (const float*)d_in[8],  (const float*)d_in[9],
        (const float*)d_in[10], (const float*)d_in[11],
        (const float*)d_in[12], (const float*)d_in[13],
        (const float*)d_in[14], (const float*)d_in[15],
        (const float*)d_in[16], (const float*)d_in[17],
        (const float*)d_in[18],
        (const float*)d_in[19], (const float*)d_in[20],
        (const float*)d_in[21],
        (float*)d_out, N, 0);
}